// Round 5
// baseline (171.211 us; speedup 1.0000x reference)
//
#include <hip/hip_runtime.h>

#define BATCH 256
#define TT 256
#define DD 384
#define HH 64
#define SCALE 0.125f
#define SHIFT 14.0f

typedef __attribute__((ext_vector_type(8))) short short8;
typedef __attribute__((ext_vector_type(4))) float floatx4;

#define KS_STRIDE 72    // Ks [256][72] bf16
#define QS_STRIDE 72    // Qs [256][72] bf16
#define VT_STRIDE 264   // Vt [64][264] bf16
#define PS_STRIDE 40    // per-wave P scratch [16][40]
#define WELEMS (3 * DD * HH)   // 73,728 bf16 = 147,456 B packed W

__device__ __forceinline__ unsigned short f2bf(float f) {
    unsigned int u = __float_as_uint(f);
    u += 0x7fffu + ((u >> 16) & 1u);
    return (unsigned short)(u >> 16);
}
__device__ __forceinline__ float bf2f(unsigned short u) {
    return __uint_as_float(((unsigned int)u) << 16);
}

// async 16B global->LDS DMA; lane i lands at ldst + i*16B (ldst wave-uniform).
__device__ __forceinline__ void gld_lds16(const void* g, void* ldst) {
    __builtin_amdgcn_global_load_lds(
        (__attribute__((address_space(1))) void*)(unsigned long long)g,
        (__attribute__((address_space(3))) void*)(unsigned int)(unsigned long long)ldst,
        16, 0, 0);
}

// 8 fp32 -> bf16 A-fragment
__device__ __forceinline__ short8 cvt8(float4 f0, float4 f1) {
    short8 a;
    a[0] = (short)f2bf(f0.x); a[1] = (short)f2bf(f0.y);
    a[2] = (short)f2bf(f0.z); a[3] = (short)f2bf(f0.w);
    a[4] = (short)f2bf(f1.x); a[5] = (short)f2bf(f1.y);
    a[6] = (short)f2bf(f1.z); a[7] = (short)f2bf(f1.w);
    return a;
}

// Pack W fp32 [D][H] -> fragment-major bf16.
// NEW k-mapping (sector-packed x loads): fragment element j of lane quad q maps to
//   d = 32*ch + 4*q + (j<4 ? j : j+12)
// i.e. j=0..3 -> d = 32ch+4q+j (bytes [16q,16q+16) of the chunk's first 64B),
//      j=4..7 -> d = 32ch+16+4q+(j-4) (same position in the second 64B).
// A and B sides use the same bijection, so the MFMA dot-product is unchanged.
__global__ void pack_w_kernel(const float* __restrict__ wq,
                              const float* __restrict__ wk,
                              const float* __restrict__ wv,
                              unsigned short* __restrict__ wf) {
    int idx = blockIdx.x * 256 + threadIdx.x;
    if (idx >= WELEMS) return;
    int j = idx & 7;
    int lane = (idx >> 3) & 63;
    int nt = (idx >> 9) & 3;
    int rem = idx >> 11;                   // ch*3 + mat
    int mat = rem % 3;
    int ch = rem / 3;
    int l16 = lane & 15, q = lane >> 4;
    int h = 16 * nt + l16;
    int d = 32 * ch + 4 * q + (j < 4 ? j : j + 12);
    const float* w = (mat == 0) ? wq : (mat == 1) ? wk : wv;
    wf[idx] = f2bf(w[d * HH + h]);
}

// One block per batch. 512 thr = 8 waves. LDS 147,456 B -> 1 block/CU.
__global__ __launch_bounds__(512, 2)
void fused_kernel(const float* __restrict__ x, const unsigned short* __restrict__ wfrag,
                  float* __restrict__ out) {
    // Phase 1 uses U.w (packed W, 147,456 B); phase-2 buffers alias it,
    // first written AFTER the post-GEMM barrier.
    __shared__ __align__(16) union LdsU {
        unsigned short w[WELEMS];                      // 147,456 B (phase 1)
        struct {
            unsigned short ks[TT * KS_STRIDE];         // 36,864 B
            unsigned short vt[HH * VT_STRIDE];         // 33,792 B
            unsigned short q[TT * QS_STRIDE];          // 36,864 B
            unsigned short p[8][16 * PS_STRIDE];       // 10,240 B
        } s;
    } U;

    const int b = blockIdx.x;
    const int tid = threadIdx.x;
    const int wave = tid >> 6;
    const int lane = tid & 63;
    const int quad = lane >> 4;
    const int l16 = lane & 15;

    const float* xb = x + (size_t)b * TT * DD;

    // Sector-packed A-fragment source: per chunk, instr-0 reads 16B at
    // row*1536 + 128*ch + 16*quad (wave = 16 rows x 64B CONTIGUOUS), instr-1
    // the next 64B. Full-sector utilization on every VMEM instruction.
    const float* xr0 = xb + (size_t)(32 * wave + l16) * DD + 4 * quad;
    const float* xr1 = xr0 + (size_t)16 * DD;

    // ---------------- Phase 1: Q,K,V = x_b @ {Wq,Wk,Wv} ----------------
    floatx4 cq[2][4] = {};
    floatx4 ck[2][4] = {};
    floatx4 cv[2][4] = {};

    // 4-chunk-deep x register pipeline (4 bufs x 4 float4 = 64 VGPR):
    // 8 waves x 4 chunks x 2KB = 64 KB in flight per CU.
    float4 xP0_0, xP0_1, xP0_2, xP0_3;
    float4 xP1_0, xP1_1, xP1_2, xP1_3;
    float4 xP2_0, xP2_1, xP2_2, xP2_3;
    float4 xP3_0, xP3_1, xP3_2, xP3_3;

    #define XLOAD(B, CH)                                   \
        B##_0 = *(const float4*)(xr0 + (CH) * 32);         \
        B##_1 = *(const float4*)(xr0 + (CH) * 32 + 16);    \
        B##_2 = *(const float4*)(xr1 + (CH) * 32);         \
        B##_3 = *(const float4*)(xr1 + (CH) * 32 + 16);

    // Prefill chunks 0-3 first: the HBM stream starts before W staging.
    XLOAD(xP0, 0)
    XLOAD(xP1, 1)
    XLOAD(xP2, 2)
    XLOAD(xP3, 3)

    // Stage all packed W into LDS: 144 granules of 1KB, 18 per wave, linear.
    #pragma unroll
    for (int t = 0; t < 18; ++t) {
        int grp = wave * 18 + t;    // wave-uniform
        gld_lds16(wfrag + (size_t)grp * 512 + lane * 8, U.w + grp * 512);
    }

    __syncthreads();   // W staged (drains vmcnt; x chunks 0-3 also landed)

    // Per chunk: consume buffer, reissue it for chunk+4, 12 W ds_read_b128,
    // 24 MFMAs. No barriers inside the sequence.
    #define GEMM_BODY(B, CH)                                                       \
        {                                                                          \
            short8 a0 = cvt8(B##_0, B##_1);                                        \
            short8 a1 = cvt8(B##_2, B##_3);                                        \
            if ((CH) + 4 < 12) { XLOAD(B, (CH) + 4) }                              \
            const unsigned short* wb = U.w + (size_t)(CH) * 12 * 512 + lane * 8;   \
            short8 wf_[12];                                                        \
            _Pragma("unroll")                                                      \
            for (int i = 0; i < 12; ++i)                                           \
                wf_[i] = *(const short8*)(wb + (size_t)i * 512);                   \
            _Pragma("unroll")                                                      \
            for (int nt = 0; nt < 4; ++nt) {                                       \
                cq[0][nt] = __builtin_amdgcn_mfma_f32_16x16x32_bf16(a0, wf_[nt], cq[0][nt], 0, 0, 0);      \
                cq[1][nt] = __builtin_amdgcn_mfma_f32_16x16x32_bf16(a1, wf_[nt], cq[1][nt], 0, 0, 0);      \
                ck[0][nt] = __builtin_amdgcn_mfma_f32_16x16x32_bf16(a0, wf_[4 + nt], ck[0][nt], 0, 0, 0);  \
                ck[1][nt] = __builtin_amdgcn_mfma_f32_16x16x32_bf16(a1, wf_[4 + nt], ck[1][nt], 0, 0, 0);  \
                cv[0][nt] = __builtin_amdgcn_mfma_f32_16x16x32_bf16(a0, wf_[8 + nt], cv[0][nt], 0, 0, 0);  \
                cv[1][nt] = __builtin_amdgcn_mfma_f32_16x16x32_bf16(a1, wf_[8 + nt], cv[1][nt], 0, 0, 0);  \
            }                                                                      \
        }

    GEMM_BODY(xP0, 0)
    GEMM_BODY(xP1, 1)
    GEMM_BODY(xP2, 2)
    GEMM_BODY(xP3, 3)
    GEMM_BODY(xP0, 4)
    GEMM_BODY(xP1, 5)
    GEMM_BODY(xP2, 6)
    GEMM_BODY(xP3, 7)
    GEMM_BODY(xP0, 8)
    GEMM_BODY(xP1, 9)
    GEMM_BODY(xP2, 10)
    GEMM_BODY(xP3, 11)
    #undef GEMM_BODY
    #undef XLOAD

    __syncthreads();   // all W-fragment reads done before overlaying with Q/Ks/Vt/P

    // C layout: row = 32*wave + 16*mi + 4*quad + r, col = 16*nt + l16
    #pragma unroll
    for (int mi = 0; mi < 2; ++mi)
      #pragma unroll
      for (int nt = 0; nt < 4; ++nt)
        #pragma unroll
        for (int r = 0; r < 4; ++r) {
            int row = 32 * wave + 16 * mi + 4 * quad + r;
            int col = 16 * nt + l16;
            U.s.q[row * QS_STRIDE + col] = f2bf(cq[mi][nt][r]);
            U.s.ks[row * KS_STRIDE + col] = f2bf(ck[mi][nt][r]);
            U.s.vt[col * VT_STRIDE + row] = f2bf(cv[mi][nt][r]);
        }

    __syncthreads();

    // ---------------- Phase 2: causal attention, fixed-shift softmax ----------------
    // wave handles row-groups g = wave and g = 15-wave: 9 key-chunks total (balanced).
    floatx4 o[2][4] = {};
    float l_run[2][4] = {{0.f, 0.f, 0.f, 0.f}, {0.f, 0.f, 0.f, 0.f}};
    unsigned short* psw = U.s.p[wave];

    #pragma unroll
    for (int gi = 0; gi < 2; ++gi) {
        int g = gi ? (15 - wave) : wave;
        int gr0 = 16 * g;
        short8 aq0 = *(const short8*)(U.s.q + (size_t)(gr0 + l16) * QS_STRIDE + quad * 8);
        short8 aq1 = *(const short8*)(U.s.q + (size_t)(gr0 + l16) * QS_STRIDE + 32 + quad * 8);
        int clast = g >> 1;
        for (int c = 0; c <= clast; ++c) {
            floatx4 s[2] = {};
            #pragma unroll
            for (int ni = 0; ni < 2; ++ni) {
                const unsigned short* kbase =
                    U.s.ks + (size_t)(32 * c + 16 * ni + l16) * KS_STRIDE + quad * 8;
                s[ni] = __builtin_amdgcn_mfma_f32_16x16x32_bf16(aq0, *(const short8*)(kbase), s[ni], 0, 0, 0);
                s[ni] = __builtin_amdgcn_mfma_f32_16x16x32_bf16(aq1, *(const short8*)(kbase + 32), s[ni], 0, 0, 0);
            }
            bool partial = (c == clast);
            #pragma unroll
            for (int r = 0; r < 4; ++r) {
                int row = gr0 + 4 * quad + r;
                float p0 = __expf(s[0][r] * SCALE - SHIFT);
                float p1 = __expf(s[1][r] * SCALE - SHIFT);
                if (partial) {
                    if (32 * c + l16 > row) p0 = 0.f;
                    if (32 * c + 16 + l16 > row) p1 = 0.f;
                }
                unsigned short b0 = f2bf(p0), b1 = f2bf(p1);
                l_run[gi][r] += bf2f(b0) + bf2f(b1);   // consistent with bf16 P fed to PV
                psw[(4 * quad + r) * PS_STRIDE + l16] = b0;
                psw[(4 * quad + r) * PS_STRIDE + 16 + l16] = b1;
            }
            short8 ap = *(const short8*)(psw + l16 * PS_STRIDE + quad * 8);
            #pragma unroll
            for (int nt = 0; nt < 4; ++nt) {
                short8 bv = *(const short8*)(U.s.vt + (size_t)(16 * nt + l16) * VT_STRIDE + 32 * c + quad * 8);
                o[gi][nt] = __builtin_amdgcn_mfma_f32_16x16x32_bf16(ap, bv, o[gi][nt], 0, 0, 0);
            }
        }
    }

    // ---------------- Epilogue: l-reduction, one reciprocal per row, store ----------------
    float* outb = out + (size_t)b * TT * HH;
    #pragma unroll
    for (int gi = 0; gi < 2; ++gi) {
        int g = gi ? (15 - wave) : wave;
        float linv[4];
        #pragma unroll
        for (int r = 0; r < 4; ++r) {
            float l = l_run[gi][r];
            l += __shfl_xor(l, 1);
            l += __shfl_xor(l, 2);
            l += __shfl_xor(l, 4);
            l += __shfl_xor(l, 8);
            linv[r] = 1.0f / l;
        }
        #pragma unroll
        for (int nt = 0; nt < 4; ++nt)
          #pragma unroll
          for (int r = 0; r < 4; ++r) {
            int row = 16 * g + 4 * quad + r;
            outb[(size_t)row * HH + 16 * nt + l16] = o[gi][nt][r] * linv[r];
          }
    }
}

extern "C" void kernel_launch(void* const* d_in, const int* in_sizes, int n_in,
                              void* d_out, int out_size, void* d_ws, size_t ws_size,
                              hipStream_t stream) {
    const float* x  = (const float*)d_in[0];
    const float* wq = (const float*)d_in[1];
    const float* wk = (const float*)d_in[2];
    const float* wv = (const float*)d_in[3];
    unsigned short* wf = (unsigned short*)d_ws;   // fragment-major W, 147,456 B
    float* o = (float*)d_out;

    pack_w_kernel<<<(WELEMS + 255) / 256, 256, 0, stream>>>(wq, wk, wv, wf);
    fused_kernel<<<BATCH, 512, 0, stream>>>(x, wf, o);
}